// Round 3
// baseline (1018.615 us; speedup 1.0000x reference)
//
#include <hip/hip_runtime.h>
#include <hip/hip_bf16.h>
#include <math.h>

#define BATCH 2
#define LSEQ 1024
#define DMODEL 1024
#define DSTATE 16
#define DMAMBA 2048
#define DTRANK 64
#define NTOK (BATCH * LSEQ)             // 2048
#define XDBL_N (DTRANK + 2 * DSTATE)    // 96

typedef __attribute__((ext_vector_type(8))) short short8;
typedef __attribute__((ext_vector_type(4))) float f32x4;

static __device__ __forceinline__ unsigned short f2bf(float f) {
    union { float f; unsigned u; } v; v.f = f;
    unsigned r = v.u + 0x7FFF + ((v.u >> 16) & 1);   // RNE
    return (unsigned short)(r >> 16);
}

// ---------------- fp32 -> bf16 elementwise (8 per thread) ----------------
__global__ __launch_bounds__(256) void cvt_bf16_kernel(
    const float* __restrict__ in, unsigned short* __restrict__ out, int n8)
{
    int i = blockIdx.x * 256 + threadIdx.x;
    if (i >= n8) return;
    const float4* p = (const float4*)(in + (size_t)i * 8);
    float4 a = p[0], b = p[1];
    unsigned short t[8];
    t[0]=f2bf(a.x); t[1]=f2bf(a.y); t[2]=f2bf(a.z); t[3]=f2bf(a.w);
    t[4]=f2bf(b.x); t[5]=f2bf(b.y); t[6]=f2bf(b.z); t[7]=f2bf(b.w);
    *(short8*)(out + (size_t)i * 8) = *(short8*)t;
}

// ---------------- fp32 [K][N] -> bf16 [N][K] transpose-convert ----------------
__global__ __launch_bounds__(256) void transpose_bf16_kernel(
    const float* __restrict__ W, unsigned short* __restrict__ Wt, int K, int N)
{
    __shared__ unsigned short tile[32][33];
    int k0 = blockIdx.y * 32, n0 = blockIdx.x * 32;
    int tx = threadIdx.x & 31, ty = threadIdx.x >> 5;   // 32 x 8
    #pragma unroll
    for (int i = 0; i < 32; i += 8)
        tile[ty + i][tx] = f2bf(W[(size_t)(k0 + ty + i) * N + n0 + tx]);
    __syncthreads();
    #pragma unroll
    for (int i = 0; i < 32; i += 8)
        Wt[(size_t)(n0 + ty + i) * K + k0 + tx] = tile[tx][ty + i];
}

// ---------------- bf16 MFMA GEMM: C_f32[M][ldc] = A_bf16[M][lda-strided] @ Bt_bf16[N][K]^T
// BM=BN=128, BK=32, 256 threads = 4 waves (2x2), 64x64 per wave.
// M, N multiples of 128; K multiple of 32.
__global__ __launch_bounds__(256) void gemm_mfma(
    const unsigned short* __restrict__ A, int lda,
    const unsigned short* __restrict__ Bt,
    float* __restrict__ C, int ldc,
    int K)
{
    __shared__ __attribute__((aligned(16))) unsigned short As[128][40];
    __shared__ __attribute__((aligned(16))) unsigned short Bs[128][40];
    int tid = threadIdx.x;
    int wave = tid >> 6, lane = tid & 63;
    int wr = wave >> 1, wc = wave & 1;
    int m0 = blockIdx.y * 128, n0 = blockIdx.x * 128;
    int srow = tid >> 1, skof = (tid & 1) * 16;     // staging: half-row per thread
    int fr = lane & 15, fk = (lane >> 4) * 8;       // fragment row / k-base

    f32x4 acc[4][4] = {};

    for (int k0 = 0; k0 < K; k0 += 32) {
        {
            const unsigned short* asrc = &A[(size_t)(m0 + srow) * lda + k0 + skof];
            *(short8*)&As[srow][skof]     = *(const short8*)asrc;
            *(short8*)&As[srow][skof + 8] = *(const short8*)(asrc + 8);
            const unsigned short* bsrc = &Bt[(size_t)(n0 + srow) * K + k0 + skof];
            *(short8*)&Bs[srow][skof]     = *(const short8*)bsrc;
            *(short8*)&Bs[srow][skof + 8] = *(const short8*)(bsrc + 8);
        }
        __syncthreads();
        short8 afr[4], bfr[4];
        #pragma unroll
        for (int i = 0; i < 4; ++i) afr[i] = *(const short8*)&As[wr * 64 + i * 16 + fr][fk];
        #pragma unroll
        for (int j = 0; j < 4; ++j) bfr[j] = *(const short8*)&Bs[wc * 64 + j * 16 + fr][fk];
        #pragma unroll
        for (int i = 0; i < 4; ++i)
            #pragma unroll
            for (int j = 0; j < 4; ++j)
                acc[i][j] = __builtin_amdgcn_mfma_f32_16x16x32_bf16(afr[i], bfr[j], acc[i][j], 0, 0, 0);
        __syncthreads();
    }

    #pragma unroll
    for (int i = 0; i < 4; ++i) {
        int rbase = m0 + wr * 64 + i * 16 + 4 * (lane >> 4);
        #pragma unroll
        for (int j = 0; j < 4; ++j) {
            int col = n0 + wc * 64 + j * 16 + (lane & 15);
            #pragma unroll
            for (int r = 0; r < 4; ++r)
                C[(size_t)(rbase + r) * ldc + col] = acc[i][j][r];
        }
    }
}

// ---------------- generic tiled fp32 GEMM: C = act(A@B + bias) ----------------
template <int ACT>
__global__ __launch_bounds__(256) void gemm_f32(
    const float* __restrict__ A, int lda,
    const float* __restrict__ B, int ldb,
    const float* __restrict__ bias,
    float* __restrict__ C, int ldc,
    int M, int N, int K)
{
    const int BM = 64, BN = 64, BK = 16;
    __shared__ float As[BK][BM + 1];
    __shared__ float Bs[BK][BN + 4];
    int tid = threadIdx.x;
    int m0 = blockIdx.y * BM;
    int n0 = blockIdx.x * BN;
    float acc[4][4] = {};
    int ty = tid >> 4, tx = tid & 15;
    int arow = tid >> 2;
    int acol = (tid & 3) * 4;
    int brow = tid >> 4;
    int bcol = (tid & 15) * 4;

    for (int k0 = 0; k0 < K; k0 += BK) {
        {
            int gm = m0 + arow;
            #pragma unroll
            for (int j = 0; j < 4; ++j) {
                int gk = k0 + acol + j;
                float v = 0.f;
                if (gm < M && gk < K) v = A[(size_t)gm * lda + gk];
                As[acol + j][arow] = v;
            }
        }
        {
            int gk = k0 + brow;
            #pragma unroll
            for (int j = 0; j < 4; ++j) {
                int gn = n0 + bcol + j;
                float v = 0.f;
                if (gk < K && gn < N) v = B[(size_t)gk * ldb + gn];
                Bs[brow][bcol + j] = v;
            }
        }
        __syncthreads();
        #pragma unroll
        for (int kk = 0; kk < BK; ++kk) {
            float ar[4], br[4];
            #pragma unroll
            for (int i = 0; i < 4; ++i) ar[i] = As[kk][ty * 4 + i];
            #pragma unroll
            for (int j = 0; j < 4; ++j) br[j] = Bs[kk][tx * 4 + j];
            #pragma unroll
            for (int i = 0; i < 4; ++i)
                #pragma unroll
                for (int j = 0; j < 4; ++j)
                    acc[i][j] = fmaf(ar[i], br[j], acc[i][j]);
        }
        __syncthreads();
    }

    #pragma unroll
    for (int i = 0; i < 4; ++i) {
        int gm = m0 + ty * 4 + i;
        if (gm >= M) continue;
        #pragma unroll
        for (int j = 0; j < 4; ++j) {
            int gn = n0 + tx * 4 + j;
            if (gn >= N) continue;
            float v = acc[i][j];
            if (bias) v += bias[gn];
            if (ACT == 1) v = (v > 20.f) ? v : log1pf(expf(v));
            C[(size_t)gm * ldc + gn] = v;
        }
    }
}

// ---------------- depthwise conv1d (k=4, pad left1/right2) + SiLU ----------------
__global__ __launch_bounds__(256) void conv_silu_kernel(
    const float* __restrict__ xz,
    const float* __restrict__ cw,
    const float* __restrict__ cb,
    float* __restrict__ xm)
{
    int idx = blockIdx.x * 256 + threadIdx.x;
    if (idx >= NTOK * DMAMBA) return;
    int c = idx & (DMAMBA - 1);
    int t = idx >> 11;
    int b = t >> 10;
    int l = t & (LSEQ - 1);
    float acc = cb[c];
    #pragma unroll
    for (int k = 0; k < 4; ++k) {
        int li = l - 1 + k;
        if (li >= 0 && li < LSEQ)
            acc = fmaf(xz[(size_t)(b * LSEQ + li) * (2 * DMAMBA) + c], cw[k * DMAMBA + c], acc);
    }
    xm[(size_t)t * DMAMBA + c] = acc / (1.f + expf(-acc));
}

// ---------------- fused selective scan + skip + gate -> bf16 y ----------------
// 16 lanes per (b,m) channel, one lane per state; y written bf16 strided into xz x-half.
__global__ __launch_bounds__(256) void scan_kernel(
    const float* __restrict__ dt,
    const float* __restrict__ xm,
    const float* __restrict__ xdbl,
    const float* __restrict__ A_log,
    const float* __restrict__ Dv,
    const float* __restrict__ zbuf,       // xz + DMAMBA, ld = 2*DMAMBA floats
    unsigned short* __restrict__ ybuf)    // (ushort*)xz, ld = 4*DMAMBA ushorts
{
    int tid = threadIdx.x;
    int s = tid & 15;
    int gl = tid >> 4;
    int g = blockIdx.x * 16 + gl;
    int m = g & (DMAMBA - 1);
    int b = g >> 11;
    float Ams = -expf(A_log[m * DSTATE + s]);
    float Dm = Dv[m];
    float state = 0.f;
    int rowbase = b * LSEQ;
    for (int l = 0; l < LSEQ; l += 4) {
        float dtv[4], uu[4], Bv[4], Cv[4];
        #pragma unroll
        for (int q = 0; q < 4; ++q) {
            int row = rowbase + l + q;
            dtv[q] = dt[(size_t)row * DMAMBA + m];
            uu[q]  = xm[(size_t)row * DMAMBA + m];
            Bv[q]  = xdbl[row * XDBL_N + DTRANK + s];
            Cv[q]  = xdbl[row * XDBL_N + DTRANK + DSTATE + s];
        }
        #pragma unroll
        for (int q = 0; q < 4; ++q) {
            int row = rowbase + l + q;
            float dA = __expf(dtv[q] * Ams);
            state = fmaf(dA, state, dtv[q] * Bv[q] * uu[q]);
            float p = state * Cv[q];
            p += __shfl_xor(p, 1);
            p += __shfl_xor(p, 2);
            p += __shfl_xor(p, 4);
            p += __shfl_xor(p, 8);
            if (s == 0) {
                float zv = zbuf[(size_t)row * (2 * DMAMBA) + m];
                float yv = (p + uu[q] * Dm) * (zv / (1.f + expf(-zv)));
                ybuf[(size_t)row * (4 * DMAMBA) + m] = f2bf(yv);
            }
        }
    }
}

extern "C" void kernel_launch(void* const* d_in, const int* in_sizes, int n_in,
                              void* d_out, int out_size, void* d_ws, size_t ws_size,
                              hipStream_t stream) {
    const float* x      = (const float*)d_in[0];
    const float* W_in   = (const float*)d_in[1];
    const float* conv_w = (const float*)d_in[2];
    const float* conv_b = (const float*)d_in[3];
    const float* A_log  = (const float*)d_in[4];
    const float* Dv     = (const float*)d_in[5];
    const float* W_x    = (const float*)d_in[6];
    const float* W_dt   = (const float*)d_in[7];
    const float* b_dt   = (const float*)d_in[8];
    const float* W_out  = (const float*)d_in[9];
    float* out = (float*)d_out;

    float* ws   = (float*)d_ws;
    float* xz   = ws;                                   // [2048][4096] f32   32 MB
    float* xm   = xz + (size_t)NTOK * 2 * DMAMBA;       // [2048][2048] f32   16 MB
    float* xdbl = xm + (size_t)NTOK * DMAMBA;           // [2048][96]   f32   0.75 MB
    float* dtb  = xdbl + (size_t)NTOK * XDBL_N;         // [2048][2048] f32   16 MB
    float* aux  = dtb + (size_t)NTOK * DMAMBA;          // 4 MB region
    // overlays (sequentially dead regions):
    unsigned short* WinT  = (unsigned short*)dtb;       // [4096][1024] bf16 (dead before dtb written)
    unsigned short* xb    = (unsigned short*)aux;       // [2048][1024] bf16
    unsigned short* WoutT = (unsigned short*)aux;       // [1024][2048] bf16 (after GEMM1)
    unsigned short* yb    = (unsigned short*)xz;        // bf16, ld 8192, cols [0,2048) (x-half reuse)

    dim3 blk(256);

    // 0a) x -> bf16
    cvt_bf16_kernel<<<dim3(NTOK * DMODEL / 8 / 256), blk, 0, stream>>>(x, xb, NTOK * DMODEL / 8);
    // 0b) W_in [1024][4096] -> WinT [4096][1024] bf16
    transpose_bf16_kernel<<<dim3(2 * DMAMBA / 32, DMODEL / 32), blk, 0, stream>>>(W_in, WinT, DMODEL, 2 * DMAMBA);

    // 1) xz = x @ W_in  (MFMA)  M=2048 N=4096 K=1024
    gemm_mfma<<<dim3(2 * DMAMBA / 128, NTOK / 128), blk, 0, stream>>>(
        xb, DMODEL, WinT, xz, 2 * DMAMBA, DMODEL);

    // 2) depthwise conv + silu -> xm
    conv_silu_kernel<<<dim3(NTOK * DMAMBA / 256), blk, 0, stream>>>(xz, conv_w, conv_b, xm);

    // 1b) W_out [2048][1024] -> WoutT [1024][2048] bf16 (aux region free now)
    transpose_bf16_kernel<<<dim3(DMODEL / 32, DMAMBA / 32), blk, 0, stream>>>(W_out, WoutT, DMAMBA, DMODEL);

    // 3) x_dbl = xm @ W_x   [2048 x 96 x 2048]  (fp32)
    gemm_f32<0><<<dim3((XDBL_N + 63) / 64, NTOK / 64), blk, 0, stream>>>(
        xm, DMAMBA, W_x, XDBL_N, nullptr, xdbl, XDBL_N, NTOK, XDBL_N, DMAMBA);

    // 4) dt = softplus(x_dbl[:,:64] @ W_dt + b_dt)   [2048 x 2048 x 64]  (fp32)
    gemm_f32<1><<<dim3(DMAMBA / 64, NTOK / 64), blk, 0, stream>>>(
        xdbl, XDBL_N, W_dt, DMAMBA, b_dt, dtb, DMAMBA, NTOK, DMAMBA, DTRANK);

    // 5) fused scan + D-skip + silu(z) gate -> yb (bf16, strided in xz x-half)
    scan_kernel<<<dim3(BATCH * DMAMBA / 16), blk, 0, stream>>>(
        dtb, xm, xdbl, A_log, Dv, xz + DMAMBA, yb);

    // 6) out = y @ W_out  (MFMA)  M=2048 N=1024 K=2048
    gemm_mfma<<<dim3(DMODEL / 128, NTOK / 128), blk, 0, stream>>>(
        yb, 4 * DMAMBA, WoutT, out, DMODEL, DMAMBA);
}

// Round 5
// 440.511 us; speedup vs baseline: 2.3123x; 2.3123x over previous
//
#include <hip/hip_runtime.h>
#include <hip/hip_bf16.h>
#include <math.h>

#define BATCH 2
#define LSEQ 1024
#define DMODEL 1024
#define DSTATE 16
#define DMAMBA 2048
#define DTRANK 64
#define NTOK (BATCH * LSEQ)             // 2048
#define NCHUNK 16
#define CLEN (LSEQ / NCHUNK)            // 64
#define NLANE (BATCH * DMAMBA * DSTATE) // 65536 scan lanes

typedef __attribute__((ext_vector_type(8))) short short8;
typedef __attribute__((ext_vector_type(4))) float f32x4;

static __device__ __forceinline__ unsigned short f2bf(float f) {
    union { float f; unsigned u; } v; v.f = f;
    unsigned r = v.u + 0x7FFF + ((v.u >> 16) & 1);   // RNE
    return (unsigned short)(r >> 16);
}

// ---------------- fp32 -> bf16 elementwise (8 per thread) ----------------
__global__ __launch_bounds__(256) void cvt_bf16_kernel(
    const float* __restrict__ in, unsigned short* __restrict__ out, int n8)
{
    int i = blockIdx.x * 256 + threadIdx.x;
    if (i >= n8) return;
    const float4* p = (const float4*)(in + (size_t)i * 8);
    float4 a = p[0], b = p[1];
    unsigned short t[8];
    t[0]=f2bf(a.x); t[1]=f2bf(a.y); t[2]=f2bf(a.z); t[3]=f2bf(a.w);
    t[4]=f2bf(b.x); t[5]=f2bf(b.y); t[6]=f2bf(b.z); t[7]=f2bf(b.w);
    *(short8*)(out + (size_t)i * 8) = *(short8*)t;
}

// ---- dt_low: xdbl128[:, 0:64] f32 -> bf16 [2048][64] ----
__global__ __launch_bounds__(256) void cvt_dtl_kernel(
    const float* __restrict__ xdbl128, unsigned short* __restrict__ dtlb)
{
    int i = blockIdx.x * 256 + threadIdx.x;     // 16384 threads, 8 elems each
    int r = i >> 3, c8 = (i & 7) * 8;
    const float* src = xdbl128 + (size_t)r * 128 + c8;
    unsigned short t[8];
    #pragma unroll
    for (int j = 0; j < 8; ++j) t[j] = f2bf(src[j]);
    *(short8*)(dtlb + (size_t)r * 64 + c8) = *(short8*)t;
}

// ---------------- fp32 [K][N] -> bf16 [Npad][K] transpose-convert (zero-fill n>=N) ----
__global__ __launch_bounds__(256) void transpose_bf16_kernel(
    const float* __restrict__ W, unsigned short* __restrict__ Wt, int K, int N)
{
    __shared__ unsigned short tile[32][33];
    int k0 = blockIdx.y * 32, n0 = blockIdx.x * 32;
    int tx = threadIdx.x & 31, ty = threadIdx.x >> 5;   // 32 x 8
    #pragma unroll
    for (int i = 0; i < 32; i += 8) {
        unsigned short v = 0;
        if (n0 + tx < N) v = f2bf(W[(size_t)(k0 + ty + i) * N + n0 + tx]);
        tile[ty + i][tx] = v;
    }
    __syncthreads();
    #pragma unroll
    for (int i = 0; i < 32; i += 8)
        Wt[(size_t)(n0 + ty + i) * K + k0 + tx] = tile[tx][ty + i];
}

// ---------------- bf16 MFMA GEMM: C_f32[M][ldc] = act(A @ Bt^T + bias) ----------------
// BM=BN=128, BK=32, 256 threads = 4 waves (2x2), 64x64 per wave.
// ACT: 0 = none, 1 = softplus
template <int ACT>
__global__ __launch_bounds__(256) void gemm_mfma(
    const unsigned short* __restrict__ A, int lda,
    const unsigned short* __restrict__ Bt,
    const float* __restrict__ bias,
    float* __restrict__ C, int ldc,
    int K)
{
    __shared__ __attribute__((aligned(16))) unsigned short As[128][40];
    __shared__ __attribute__((aligned(16))) unsigned short Bs[128][40];
    int tid = threadIdx.x;
    int wave = tid >> 6, lane = tid & 63;
    int wr = wave >> 1, wc = wave & 1;
    int m0 = blockIdx.y * 128, n0 = blockIdx.x * 128;
    int srow = tid >> 1, skof = (tid & 1) * 16;
    int fr = lane & 15, fk = (lane >> 4) * 8;

    f32x4 acc[4][4] = {};

    for (int k0 = 0; k0 < K; k0 += 32) {
        {
            const unsigned short* asrc = &A[(size_t)(m0 + srow) * lda + k0 + skof];
            *(short8*)&As[srow][skof]     = *(const short8*)asrc;
            *(short8*)&As[srow][skof + 8] = *(const short8*)(asrc + 8);
            const unsigned short* bsrc = &Bt[(size_t)(n0 + srow) * K + k0 + skof];
            *(short8*)&Bs[srow][skof]     = *(const short8*)bsrc;
            *(short8*)&Bs[srow][skof + 8] = *(const short8*)(bsrc + 8);
        }
        __syncthreads();
        short8 afr[4], bfr[4];
        #pragma unroll
        for (int i = 0; i < 4; ++i) afr[i] = *(const short8*)&As[wr * 64 + i * 16 + fr][fk];
        #pragma unroll
        for (int j = 0; j < 4; ++j) bfr[j] = *(const short8*)&Bs[wc * 64 + j * 16 + fr][fk];
        #pragma unroll
        for (int i = 0; i < 4; ++i)
            #pragma unroll
            for (int j = 0; j < 4; ++j)
                acc[i][j] = __builtin_amdgcn_mfma_f32_16x16x32_bf16(afr[i], bfr[j], acc[i][j], 0, 0, 0);
        __syncthreads();
    }

    #pragma unroll
    for (int i = 0; i < 4; ++i) {
        int rbase = m0 + wr * 64 + i * 16 + 4 * (lane >> 4);
        #pragma unroll
        for (int j = 0; j < 4; ++j) {
            int col = n0 + wc * 64 + j * 16 + (lane & 15);
            #pragma unroll
            for (int r = 0; r < 4; ++r) {
                float v = acc[i][j][r];
                if (bias) v += bias[col];
                if (ACT == 1) v = (v > 20.f) ? v : log1pf(expf(v));
                C[(size_t)(rbase + r) * ldc + col] = v;
            }
        }
    }
}

// ---------------- depthwise conv1d (k=4, pad left1/right2) + SiLU, dual f32/bf16 out ----
__global__ __launch_bounds__(256) void conv_silu_kernel(
    const float* __restrict__ xz,
    const float* __restrict__ cw,
    const float* __restrict__ cb,
    float* __restrict__ xm,
    unsigned short* __restrict__ xmb)
{
    int idx = blockIdx.x * 256 + threadIdx.x;
    if (idx >= NTOK * DMAMBA) return;
    int c = idx & (DMAMBA - 1);
    int t = idx >> 11;
    int b = t >> 10;
    int l = t & (LSEQ - 1);
    float acc = cb[c];
    #pragma unroll
    for (int k = 0; k < 4; ++k) {
        int li = l - 1 + k;
        if (li >= 0 && li < LSEQ)
            acc = fmaf(xz[(size_t)(b * LSEQ + li) * (2 * DMAMBA) + c], cw[k * DMAMBA + c], acc);
    }
    float s = acc / (1.f + expf(-acc));
    xm[(size_t)t * DMAMBA + c] = s;
    xmb[(size_t)t * DMAMBA + c] = f2bf(s);
}

// ---------------- chunked selective scan ----------------
// Phase A: per (channel-block, chunk): aprod = prod(dA), send = end-state from 0.
__global__ __launch_bounds__(256) void scanA_kernel(
    const float* __restrict__ dt,
    const float* __restrict__ xm,
    const float* __restrict__ xdbl,     // ld 128, B at col 64+s
    const float* __restrict__ A_log,
    float* __restrict__ aprod_buf,
    float* __restrict__ send_buf)
{
    int tid = threadIdx.x;
    int s = tid & 15;
    int g = blockIdx.x * 16 + (tid >> 4);
    int c = blockIdx.y;
    int m = g & (DMAMBA - 1);
    int b = g >> 11;
    float Ams = -expf(A_log[m * DSTATE + s]);
    float ap = 1.f, se = 0.f;
    int row0 = b * LSEQ + c * CLEN;
    for (int l = 0; l < CLEN; l += 4) {
        float dtv[4], uu[4], Bv[4];
        #pragma unroll
        for (int q = 0; q < 4; ++q) {
            int row = row0 + l + q;
            dtv[q] = dt[(size_t)row * DMAMBA + m];
            uu[q]  = xm[(size_t)row * DMAMBA + m];
            Bv[q]  = xdbl[(size_t)row * 128 + DTRANK + s];
        }
        #pragma unroll
        for (int q = 0; q < 4; ++q) {
            float dA = __expf(dtv[q] * Ams);
            se = fmaf(dA, se, dtv[q] * Bv[q] * uu[q]);
            ap *= dA;
        }
    }
    int li = blockIdx.x * 256 + tid;    // == g*16+s
    aprod_buf[(size_t)c * NLANE + li] = ap;
    send_buf[(size_t)c * NLANE + li] = se;
}

// Phase B: exclusive combine over chunks per lane. S(c) = send(c) + aprod(c)*S(c-1).
__global__ __launch_bounds__(256) void scanB_kernel(
    const float* __restrict__ aprod_buf,
    const float* __restrict__ send_buf,
    float* __restrict__ sin_buf)
{
    int li = blockIdx.x * 256 + threadIdx.x;
    float sp = 0.f;
    #pragma unroll
    for (int c = 0; c < NCHUNK; ++c) {
        float a = aprod_buf[(size_t)c * NLANE + li];
        float e = send_buf[(size_t)c * NLANE + li];
        sin_buf[(size_t)c * NLANE + li] = sp;
        sp = e + a * sp;
    }
}

// Phase C: replay chunk from entry state; C-dot, D-skip, silu(z) gate, bf16 y out.
__global__ __launch_bounds__(256) void scanC_kernel(
    const float* __restrict__ dt,
    const float* __restrict__ xm,
    const float* __restrict__ xdbl,
    const float* __restrict__ A_log,
    const float* __restrict__ Dv,
    const float* __restrict__ sin_buf,
    const float* __restrict__ zbuf,       // xz + DMAMBA, ld = 2*DMAMBA floats
    unsigned short* __restrict__ ybuf)    // (ushort*)xz, ld = 4*DMAMBA ushorts
{
    int tid = threadIdx.x;
    int s = tid & 15;
    int g = blockIdx.x * 16 + (tid >> 4);
    int c = blockIdx.y;
    int m = g & (DMAMBA - 1);
    int b = g >> 11;
    float Ams = -expf(A_log[m * DSTATE + s]);
    float Dm = Dv[m];
    int li = blockIdx.x * 256 + tid;
    float state = sin_buf[(size_t)c * NLANE + li];
    int row0 = b * LSEQ + c * CLEN;
    for (int l = 0; l < CLEN; l += 4) {
        float dtv[4], uu[4], Bv[4], Cv[4];
        #pragma unroll
        for (int q = 0; q < 4; ++q) {
            int row = row0 + l + q;
            dtv[q] = dt[(size_t)row * DMAMBA + m];
            uu[q]  = xm[(size_t)row * DMAMBA + m];
            Bv[q]  = xdbl[(size_t)row * 128 + DTRANK + s];
            Cv[q]  = xdbl[(size_t)row * 128 + DTRANK + DSTATE + s];
        }
        #pragma unroll
        for (int q = 0; q < 4; ++q) {
            int row = row0 + l + q;
            float dA = __expf(dtv[q] * Ams);
            state = fmaf(dA, state, dtv[q] * Bv[q] * uu[q]);
            float p = state * Cv[q];
            p += __shfl_xor(p, 1);
            p += __shfl_xor(p, 2);
            p += __shfl_xor(p, 4);
            p += __shfl_xor(p, 8);
            if (s == 0) {
                float zv = zbuf[(size_t)row * (2 * DMAMBA) + m];
                float yv = (p + uu[q] * Dm) * (zv / (1.f + expf(-zv)));
                ybuf[(size_t)row * (4 * DMAMBA) + m] = f2bf(yv);
            }
        }
    }
}

extern "C" void kernel_launch(void* const* d_in, const int* in_sizes, int n_in,
                              void* d_out, int out_size, void* d_ws, size_t ws_size,
                              hipStream_t stream) {
    const float* x      = (const float*)d_in[0];
    const float* W_in   = (const float*)d_in[1];
    const float* conv_w = (const float*)d_in[2];
    const float* conv_b = (const float*)d_in[3];
    const float* A_log  = (const float*)d_in[4];
    const float* Dv     = (const float*)d_in[5];
    const float* W_x    = (const float*)d_in[6];
    const float* W_dt   = (const float*)d_in[7];
    const float* b_dt   = (const float*)d_in[8];
    const float* W_out  = (const float*)d_in[9];
    float* out = (float*)d_out;

    const size_t M1 = 1048576;
    float* ws      = (float*)d_ws;
    float* xz      = ws;                         // [2048][4096] f32  32MB   (gemm1 -> conv/scanC; x-half reused as bf16 y)
    float* xm      = xz + 8 * M1;                // [2048][2048] f32  16MB
    float* dtb     = xm + 4 * M1;                // [2048][2048] f32  16MB
    float* xdbl128 = dtb + 4 * M1;               // [2048][128]  f32   1MB
    float* scanR   = xdbl128 + 2048 * 128;       // 12MB scan region (3 x 1M floats)
    float* aprod   = scanR;                      // [16][65536] f32
    float* send    = scanR + M1;
    float* sinb    = scanR + 2 * M1;
    // overlays inside scanR (dead before scanA writes):
    unsigned short* xb   = (unsigned short*)scanR;            // [2048][1024] bf16 (dead after gemm1)
    unsigned short* WinT = (unsigned short*)(scanR + M1);     // [4096][1024] bf16 (dead after gemm1)
    unsigned short* xmb  = (unsigned short*)scanR;            // [2048][2048] bf16 (conv -> gemm3)
    float* tail    = scanR + 3 * M1;
    unsigned short* WoutT = (unsigned short*)tail;            // [1024][2048] bf16 4MB
    unsigned short* WxT   = (unsigned short*)(tail + M1);     // [128][2048] bf16 0.5MB
    unsigned short* WdtT  = WxT + 128 * 2048;                 // [2048][64] bf16 0.25MB
    unsigned short* dtlb  = WdtT + 2048 * 64;                 // [2048][64] bf16 0.25MB
    unsigned short* yb    = (unsigned short*)xz;              // bf16 y, ld 8192, cols [0,2048)

    dim3 blk(256);

    // 0a) x -> bf16
    cvt_bf16_kernel<<<dim3(NTOK * DMODEL / 8 / 256), blk, 0, stream>>>(x, xb, NTOK * DMODEL / 8);
    // 0b) W_in [1024][4096] -> WinT [4096][1024]
    transpose_bf16_kernel<<<dim3(4096 / 32, 1024 / 32), blk, 0, stream>>>(W_in, WinT, DMODEL, 2 * DMAMBA);

    // 1) xz = x @ W_in   M=2048 N=4096 K=1024
    gemm_mfma<0><<<dim3(32, 16), blk, 0, stream>>>(xb, DMODEL, WinT, nullptr, xz, 2 * DMAMBA, DMODEL);

    // 2) conv + silu -> xm (f32) + xmb (bf16)
    conv_silu_kernel<<<dim3(NTOK * DMAMBA / 256), blk, 0, stream>>>(xz, conv_w, conv_b, xm, xmb);

    // weight preps (aux regions free as needed)
    transpose_bf16_kernel<<<dim3(1024 / 32, 2048 / 32), blk, 0, stream>>>(W_out, WoutT, DMAMBA, DMODEL);
    transpose_bf16_kernel<<<dim3(128 / 32, 2048 / 32), blk, 0, stream>>>(W_x, WxT, DMAMBA, 96);
    transpose_bf16_kernel<<<dim3(2048 / 32, 64 / 32), blk, 0, stream>>>(W_dt, WdtT, DTRANK, DMAMBA);

    // 3) xdbl128 = xmb @ W_x (padded N=128)   M=2048 N=128 K=2048
    gemm_mfma<0><<<dim3(1, 16), blk, 0, stream>>>(xmb, DMAMBA, WxT, nullptr, xdbl128, 128, DMAMBA);

    // 3b) dt_low -> bf16
    cvt_dtl_kernel<<<dim3(64), blk, 0, stream>>>(xdbl128, dtlb);

    // 4) dtb = softplus(dt_low @ W_dt + b_dt)   M=2048 N=2048 K=64
    gemm_mfma<1><<<dim3(16, 16), blk, 0, stream>>>(dtlb, DTRANK, WdtT, b_dt, dtb, DMAMBA, DTRANK);

    // 5) chunked scan
    scanA_kernel<<<dim3(256, NCHUNK), blk, 0, stream>>>(dtb, xm, xdbl128, A_log, aprod, send);
    scanB_kernel<<<dim3(NLANE / 256), blk, 0, stream>>>(aprod, send, sinb);
    scanC_kernel<<<dim3(256, NCHUNK), blk, 0, stream>>>(dtb, xm, xdbl128, A_log, Dv, sinb, xz + DMAMBA, yb);

    // 6) out = y @ W_out   M=2048 N=1024 K=2048
    gemm_mfma<0><<<dim3(8, 16), blk, 0, stream>>>(yb, 4 * DMAMBA, WoutT, nullptr, out, DMODEL, DMAMBA);
}